// Round 14
// baseline (148.375 us; speedup 1.0000x reference)
//
#include <hip/hip_runtime.h>
#include <hip/hip_bf16.h>
#include <math.h>

// Problem constants (fixed by setup_inputs)
constexpr int B_ = 32;
constexpr int P_ = 24564;
constexpr int C_ = 81;
constexpr int K_ = 200;

constexpr int NCH = 64;           // chunks per image
constexpr int CPR = 384;          // rows per chunk; 64*384 = 24576 >= 24564
constexpr int SCAP = 1024;        // per-block LDS staging capacity (expect ~404)
constexpr int CAP  = 512;         // per-task candidate capacity (expect ~322)
constexpr float T_SEL = 0.9869f;  // static prune threshold; mean count ~322 > 200 (6.8 sigma)
                                  // soundness: count>=200 above T => true top-200 all > T;
                                  // violations detected at runtime -> exact fallback.
// All candidate scores lie in (T_SEL, 1.0) => key bits[63:51] constant =>
// bits[50:43] are the discriminating radix digit for the cut.

// ---------------------------------------------------------------------------
// K1 (only conf pass): stream slab coalesced, stage score>T candidates in LDS,
// reserve per-class ranges with ONE global atomic per (block,class), scatter.
// ---------------------------------------------------------------------------
__global__ __launch_bounds__(256) void k_filter(const float* __restrict__ conf,
                                                unsigned long long* __restrict__ cand,
                                                unsigned* __restrict__ cnt,
                                                unsigned* __restrict__ bflag) {
    __shared__ unsigned long long skey[SCAP];   // 8 KB
    __shared__ unsigned short scls[SCAP];       // 2 KB
    __shared__ unsigned scnt[C_], sbase[C_], scnt2[C_];
    __shared__ unsigned sn;
    const int bid = blockIdx.x;
    const int b = bid / NCH, ch = bid % NCH;
    const int tid = threadIdx.x;

    for (int i = tid; i < C_; i += 256) { scnt[i] = 0; scnt2[i] = 0; }
    if (tid == 0) sn = 0;
    __syncthreads();

    const int p0 = ch * CPR;
    const int rows = min(CPR, P_ - p0);
    const float* slab = conf + ((size_t)b * P_ + (size_t)p0) * C_;
    const int n4 = rows * C_ / 4;               // rows%4==0 -> exact
    for (int g = tid; g < n4; g += 256) {
        float4 v = ((const float4*)slab)[g];
        int e = g * 4;
        int c = e % C_;
        int pl = e / C_;
        float s[4] = {v.x, v.y, v.z, v.w};
#pragma unroll
        for (int j = 0; j < 4; ++j) {
            int cj = c + j, pj = pl;
            if (cj >= C_) { cj -= C_; pj += 1; }
            float sv = s[j];
            if (sv > T_SEL && cj != 0) {        // class 0 (background) never output
                unsigned pos = atomicAdd(&sn, 1u);
                if (pos < (unsigned)SCAP) {
                    unsigned pg = (unsigned)(p0 + pj);
                    skey[pos] = ((unsigned long long)__float_as_uint(sv) << 32) | (~pg);
                    scls[pos] = (unsigned short)cj;
                    atomicAdd(&scnt[cj], 1u);
                } else {
                    bflag[b] = 1u;              // staging overflow -> image fallback
                }
            }
        }
    }
    __syncthreads();
    if (tid < C_) sbase[tid] = scnt[tid] ? atomicAdd(&cnt[b * C_ + tid], scnt[tid]) : 0u;
    __syncthreads();
    const int m = (int)min(sn, (unsigned)SCAP);
    for (int i = tid; i < m; i += 256) {
        int c = scls[i];
        unsigned pos = sbase[c] + atomicAdd(&scnt2[c], 1u);
        if (pos < (unsigned)CAP)
            cand[((size_t)(b * C_ + c)) * CAP + pos] = skey[i];
        // pos >= CAP  =>  cnt[task] > CAP  => task falls back (detected in k_nms)
    }
}

// ---------------------------------------------------------------------------
// K2: reg-staged keys -> radix cut (per-wave redundant suffix scan, wave-agg
// compact) -> n-bounded full-u64 rank-sort -> decode by rank -> eager IoU
// masks (sentinel columns, diagonal post-mask, inline rownz publish) ->
// wave-0 slot-bounded bit scan -> direct global output.
// ---------------------------------------------------------------------------
__global__ __launch_bounds__(256) void k_nms(const unsigned long long* __restrict__ cand,
                                             const unsigned* __restrict__ cnt,
                                             const unsigned* __restrict__ bflag,
                                             const float* __restrict__ conf,
                                             const float* __restrict__ loc,
                                             const float* __restrict__ prior,
                                             float* __restrict__ out) {
#pragma clang fp contract(off)
    __shared__ __align__(16) unsigned long long masks[K_][4];   // 6400 B
    __shared__ __align__(16) unsigned long long top[256];       // 2048 B (cut survivors)
    __shared__ __align__(16) float4 bbox[K_];                   // 3200 B rank-indexed
    __shared__ float sc[K_], bar[K_];
    __shared__ unsigned char vflag[K_];
    __shared__ unsigned long long keepw[4];
    __shared__ unsigned kpre[4];
    __shared__ unsigned rowsnz32[8];            // per-32-row nonzero bits
    __shared__ unsigned long long sh_prefix;
    __shared__ unsigned sh_rank, sh_cnt2;

    // aliases inside masks[] (all dead before the IoU mask build):
    unsigned long long* buf = &masks[0][0];             // 512 u64 (fb / fat staging)
    unsigned* rs_hist = (unsigned*)&masks[128][0];      // 256 u32 (cut hist / fb radix)
    unsigned* rs_sf   = (unsigned*)&masks[160][0];      // 256 u32 (fb radix)

    const int bid = blockIdx.x;
    const int b = bid / C_, c = bid % C_;
    const int tid = threadIdx.x;
    const int lane = tid & 63;
    float* obase = out + ((size_t)(b * C_ + c)) * (K_ * 5);

    if (c == 0) {                               // background rows: all zeros
        float4 z = make_float4(0.f, 0.f, 0.f, 0.f);
        for (int i = tid; i < K_ * 5 / 4; i += 256) ((float4*)obase)[i] = z;
        return;
    }

    const int task = b * C_ + c;
    const unsigned long long* crow = cand + (size_t)task * CAP;
    const unsigned cn = cnt[task];
    const bool fb = (bflag[b] != 0u) || (cn < (unsigned)K_) || (cn > (unsigned)CAP);

    int n;
    int snum = 0;                               // survivor count in top[]
    bool fat = false;
    if (!fb) {
        n = (int)cn;                            // 200 <= n <= CAP
        const unsigned long long k1 = (tid < n)       ? crow[tid]       : 0ull;
        const unsigned long long k2 = (tid + 256 < n) ? crow[tid + 256] : 0ull;
        if (n <= 256) {
            top[tid] = k1;
            snum = n;
            __syncthreads();
        } else {
            rs_hist[tid] = 0u;
            top[tid] = 0ull;
            if (tid == 0) sh_cnt2 = 0u;
            __syncthreads();
            atomicAdd(&rs_hist[(unsigned)((k1 >> 43) & 255ull)], 1u);   // tid < n (n>256)
            if (tid + 256 < n)
                atomicAdd(&rs_hist[(unsigned)((k2 >> 43) & 255ull)], 1u);
            __syncthreads();
            // per-wave REDUNDANT suffix scan over 256 bins (4 bins/lane):
            // identical inputs -> identical (cut, fat) in registers in every
            // wave; removes the publish barrier.
            unsigned cut;
            {
                const int l = lane;
                uint4 h = *(const uint4*)&rs_hist[l * 4];
                unsigned s3 = h.w;
                unsigned s2 = h.z + s3;
                unsigned s1 = h.y + s2;
                unsigned s0 = h.x + s1;
                unsigned acc = s0;
                for (int off = 1; off < 64; off <<= 1) {
                    unsigned o = __shfl_down(acc, off, 64);
                    if (l + off < 64) acc += o;
                }
                const unsigned suf_after = acc - s0;     // sum over lanes > l
                unsigned long long bal = __ballot(s0 + suf_after >= (unsigned)K_);
                const int hl = 63 - __builtin_clzll(bal);   // lane 0 suffix = n >= 257
                int kk; unsigned sufk;
                if      (s3 + suf_after >= (unsigned)K_) { kk = 3; sufk = s3 + suf_after; }
                else if (s2 + suf_after >= (unsigned)K_) { kk = 2; sufk = s2 + suf_after; }
                else if (s1 + suf_after >= (unsigned)K_) { kk = 1; sufk = s1 + suf_after; }
                else                                     { kk = 0; sufk = s0 + suf_after; }
                cut = (unsigned)__shfl(l * 4 + kk, hl, 64);
                unsigned sufhl = (unsigned)__shfl((int)sufk, hl, 64);
                fat = (sufhl > 256u);
            }
            if (!fat) {
                // wave-aggregated compact of survivors into top[] (exact set)
                {
                    bool q = ((unsigned)((k1 >> 43) & 255ull) >= cut);   // tid < n
                    unsigned long long bal = __ballot(q);
                    unsigned pre = (unsigned)__popcll(bal & ((1ull << lane) - 1ull));
                    unsigned wb = 0;
                    if (lane == 0) {
                        unsigned cw = (unsigned)__popcll(bal);
                        if (cw) wb = atomicAdd(&sh_cnt2, cw);
                    }
                    wb = (unsigned)__shfl((int)wb, 0, 64);
                    if (q) top[wb + pre] = k1;
                }
                {
                    bool q = (tid + 256 < n) && ((unsigned)((k2 >> 43) & 255ull) >= cut);
                    unsigned long long bal = __ballot(q);
                    unsigned pre = (unsigned)__popcll(bal & ((1ull << lane) - 1ull));
                    unsigned wb = 0;
                    if (lane == 0) {
                        unsigned cw = (unsigned)__popcll(bal);
                        if (cw) wb = atomicAdd(&sh_cnt2, cw);
                    }
                    wb = (unsigned)__shfl((int)wb, 0, 64);
                    if (q) top[wb + pre] = k2;
                }
                __syncthreads();
                snum = (int)sh_cnt2;            // 200..256
            } else {
                // degenerate digit distribution (essentially never): stage 512
                buf[tid] = k1;
                buf[tid + 256] = k2;
                __syncthreads();
            }
        }
    } else {
        // ---- exact fallback from the strided global column (rare/never) ----
        for (int i = tid; i < CAP; i += 256) buf[i] = 0ull;
        const float* col = conf + (size_t)b * P_ * C_ + c;
        unsigned lc = 0;
        for (int p = tid; p < P_; p += 256)
            if (col[(size_t)p * C_] > 0.01f) lc++;
        rs_sf[tid] = lc;
        __syncthreads();
        for (int off = 128; off > 0; off >>= 1) {
            if (tid < off) rs_sf[tid] += rs_sf[tid + off];
            __syncthreads();
        }
        const unsigned total = rs_sf[0];
        unsigned long long t200v = 1ull;
        if (total > (unsigned)K_) {
            if (tid == 0) { sh_prefix = 0ull; sh_rank = (unsigned)K_; }
            __syncthreads();
            for (int d = 7; d >= 0; --d) {
                rs_hist[tid] = 0;
                __syncthreads();
                const unsigned long long pref = sh_prefix;
                const unsigned rank = sh_rank;
                for (int p = tid; p < P_; p += 256) {
                    float sv = col[(size_t)p * C_];
                    if (sv > 0.01f) {
                        unsigned long long key =
                            ((unsigned long long)__float_as_uint(sv) << 32) | (~(unsigned)p);
                        bool match = (d == 7) || (((key ^ pref) >> ((d + 1) * 8)) == 0ull);
                        if (match) atomicAdd(&rs_hist[(unsigned)((key >> (d * 8)) & 255ull)], 1u);
                    }
                }
                __syncthreads();
                rs_sf[tid] = rs_hist[tid];
                __syncthreads();
                for (int off = 1; off < 256; off <<= 1) {
                    unsigned v2 = (tid + off < 256) ? rs_sf[tid + off] : 0u;
                    __syncthreads();
                    rs_sf[tid] += v2;
                    __syncthreads();
                }
                if (rs_sf[tid] >= rank && (tid == 255 || rs_sf[tid + 1] < rank)) {
                    sh_prefix = pref | ((unsigned long long)tid << (d * 8));
                    sh_rank = rank - ((tid == 255) ? 0u : rs_sf[tid + 1]);
                }
                __syncthreads();
            }
            t200v = sh_prefix;
        }
        if (tid == 0) sh_cnt2 = 0;
        __syncthreads();
        for (int p = tid; p < P_; p += 256) {
            float sv = col[(size_t)p * C_];
            if (sv > 0.01f) {
                unsigned long long key =
                    ((unsigned long long)__float_as_uint(sv) << 32) | (~(unsigned)p);
                if (key >= t200v) {
                    unsigned pos = atomicAdd(&sh_cnt2, 1u);
                    if (pos < (unsigned)CAP) buf[pos] = key;   // <=200 qualify (keys unique)
                }
            }
        }
        __syncthreads();
        n = (int)min(sh_cnt2, (unsigned)CAP);   // <= 200
        top[tid] = (tid < n) ? buf[tid] : 0ull;
        snum = n;
        __syncthreads();
    }

    const int nsel = min(n, K_);

    // ---- full-u64 rank-sort (n-bounded) and decode scattered by rank -------
    auto decode_to = [&](unsigned long long key, int r) {
        unsigned ub = (unsigned)(key >> 32);
        unsigned p = ~((unsigned)key);
        float score = __uint_as_float(ub);
        bool v = ((ub & 0x7F800000u) != 0x7F800000u);   // isfinite
        const float4 l4 = ((const float4*)loc)[(size_t)b * P_ + p];
        const float4 p4 = ((const float4*)prior)[p];
        float cx = p4.x + (l4.x * 0.1f) * p4.z;
        float cy = p4.y + (l4.y * 0.1f) * p4.w;
        float w  = p4.z * expf(l4.z * 0.2f);
        float h  = p4.w * expf(l4.w * 0.2f);
        float x1 = cx - w * 0.5f;
        float y1 = cy - h * 0.5f;
        float x2 = x1 + w;
        float y2 = y1 + h;
        bbox[r] = make_float4(x1, y1, x2, y2);
        sc[r] = score;
        bar[r] = (x2 - x1) * (y2 - y1);
        vflag[r] = v ? (unsigned char)1 : (unsigned char)0;
    };

    if (tid < 8) rowsnz32[tid] = 0u;            // init before the build barrier
    if (!fat) {
        const unsigned long long k = top[tid];
        int r = 0;
        const int mm = (snum + 3) & ~3;         // zeros beyond snum never outrank k
        for (int i = 0; i < mm; i += 4) {
            ulonglong2 a = *(const ulonglong2*)&top[i];
            ulonglong2 d = *(const ulonglong2*)&top[i + 2];
            r += (a.x > k) + (a.y > k) + (d.x > k) + (d.y > k);
        }
        if (k != 0ull && r < K_) decode_to(k, r);
    } else {
        const unsigned long long k1 = buf[tid];
        const unsigned long long k2 = buf[tid + 256];
        int r1 = 0, r2 = 0;
        for (int i = 0; i < CAP; i += 4) {
            ulonglong2 a = *(const ulonglong2*)&buf[i];
            ulonglong2 d = *(const ulonglong2*)&buf[i + 2];
            r1 += (a.x > k1) + (a.y > k1) + (d.x > k1) + (d.y > k1);
            r2 += (a.x > k2) + (a.y > k2) + (d.x > k2) + (d.y > k2);
        }
        if (k1 != 0ull && r1 < K_) decode_to(k1, r1);
        if (k2 != 0ull && r2 < K_) decode_to(k2, r2);
    }
    if (tid >= nsel && tid < K_) {              // tail rows: sentinel (never intersect)
        bbox[tid] = make_float4(1e30f, 1e30f, 1e30f, 1e30f);
        sc[tid] = 0.f; bar[tid] = 0.f; vflag[tid] = 0;
    }
    __syncthreads();                            // aliases dead -> masks writable

    // ---- eager IoU masks: sentinel columns, guard-free predicate, diagonal
    // post-mask, inline rownz publish. RN(inter/uni) > 0.45f <=> inter > M*uni
    // (exact in f64: M is the 0.45f..nextup midpoint; tie rounds to 0.45f).
    const double M_IOU = 0.5 * ((double)__uint_as_float(0x3EE66666u) +
                                (double)__uint_as_float(0x3EE66667u));
    const int nv = nsel;
    const int wid = tid >> 6;

    float4 jb[4]; float jar[4];
#pragma unroll
    for (int w = 0; w < 4; ++w) {
        int j = w * 64 + lane;
        bool in = (j < K_);
        jb[w]  = in ? bbox[j] : make_float4(1e30f, 1e30f, 1e30f, 1e30f);
        jar[w] = in ? bar[j] : 0.f;
    }

    for (int i = wid; i < nv; i += 4) {
        float4 rb = bbox[i];
        float r_ar = bar[i];
        const int w0 = i >> 6;
        const unsigned long long dmask = (0xFFFFFFFFFFFFFFFEull << (i & 63));
        bool nz = false;
#pragma unroll
        for (int w = 0; w < 4; ++w) {
            if (w >= w0) {
                float xx1 = fmaxf(rb.x, jb[w].x);
                float yy1 = fmaxf(rb.y, jb[w].y);
                float xx2 = fminf(rb.z, jb[w].z);
                float yy2 = fminf(rb.w, jb[w].w);
                float iw = fmaxf(xx2 - xx1, 0.0f);
                float ih = fmaxf(yy2 - yy1, 0.0f);
                float inter = iw * ih;
                float uni = (r_ar + jar[w]) - inter;
                bool pred = (uni > 0.0f) && ((double)inter > M_IOU * (double)uni);
                unsigned long long m = __ballot(pred);
                if (w == w0) m &= dmask;        // enforce j > i on diagonal word
                if (lane == 0) masks[i][w] = m;
                nz |= (m != 0ull);
            }
        }
        if (lane == 0 && nz)
            atomicOr(&rowsnz32[i >> 5], 1u << (i & 31));
    }
    __syncthreads();

    // ---- greedy suppression: wave 0, uniform lanes, kept-nonzero-rows loop.
    if (tid < 64) {
        const int l = tid;
        unsigned long long V0 = __ballot((l       < nv) && vflag[l]);
        unsigned long long V1 = __ballot((64 + l  < nv) && vflag[64 + l]);
        unsigned long long V2 = __ballot((128 + l < nv) && vflag[128 + l]);
        unsigned long long V3 = __ballot((192 + l < nv) && vflag[192 + l]);
        unsigned long long R0 = ((((unsigned long long)rowsnz32[1]) << 32) | rowsnz32[0]) & V0;
        unsigned long long R1 = ((((unsigned long long)rowsnz32[3]) << 32) | rowsnz32[2]) & V1;
        unsigned long long R2 = ((((unsigned long long)rowsnz32[5]) << 32) | rowsnz32[4]) & V2;
        unsigned long long R3 = ((((unsigned long long)rowsnz32[7]) << 32) | rowsnz32[6]) & V3;

        unsigned long long S0 = 0, S1 = 0, S2 = 0, S3 = 0;
        while (true) {
            unsigned long long t;
            int i = -1;
            if ((t = R0 & ~S0) != 0ull)      i = (int)__builtin_ctzll(t);
            else if ((t = R1 & ~S1) != 0ull) i = 64 + (int)__builtin_ctzll(t);
            else if ((t = R2 & ~S2) != 0ull) i = 128 + (int)__builtin_ctzll(t);
            else if ((t = R3 & ~S3) != 0ull) i = 192 + (int)__builtin_ctzll(t);
            if (i < 0) break;
            const unsigned long long bit = 1ull << (i & 63);
            const int slot = i >> 6;
            // OR only words w >= slot (lower words are structurally zero)
            if (slot == 0) {
                R0 ^= bit;
                S0 |= masks[i][0]; S1 |= masks[i][1]; S2 |= masks[i][2]; S3 |= masks[i][3];
            } else if (slot == 1) {
                R1 ^= bit;
                S1 |= masks[i][1]; S2 |= masks[i][2]; S3 |= masks[i][3];
            } else if (slot == 2) {
                R2 ^= bit;
                S2 |= masks[i][2]; S3 |= masks[i][3];
            } else {
                R3 ^= bit;
                S3 |= masks[i][3];
            }
        }
        if (l == 0) {
            unsigned long long K0 = V0 & ~S0, K1 = V1 & ~S1, K2 = V2 & ~S2, K3 = V3 & ~S3;
            keepw[0] = K0; keepw[1] = K1; keepw[2] = K2; keepw[3] = K3;
            kpre[0] = 0;
            kpre[1] = (unsigned)__popcll(K0);
            kpre[2] = kpre[1] + (unsigned)__popcll(K1);
            kpre[3] = kpre[2] + (unsigned)__popcll(K2);
        }
    }
    __syncthreads();

    // ---- direct global output: kept rows scattered, tail zero-filled -------
    if (tid < K_) {
        int w = tid >> 6, bit = tid & 63;
        if ((keepw[w] >> bit) & 1ull) {
            unsigned slot = kpre[w] + (unsigned)__popcll(keepw[w] & ((1ull << bit) - 1ull));
            float4 bb = bbox[tid];
            float* o = obase + slot * 5;
            o[0] = sc[tid]; o[1] = bb.x; o[2] = bb.y; o[3] = bb.z; o[4] = bb.w;
        }
    }
    {
        const unsigned keptTotal = kpre[3] + (unsigned)__popcll(keepw[3]);
        const int zbase = (int)keptTotal * 5;
        const int ztot = K_ * 5 - zbase;
        for (int e = tid; e < ztot; e += 256) obase[zbase + e] = 0.0f;
    }
}

// ---------------------------------------------------------------------------
extern "C" void kernel_launch(void* const* d_in, const int* in_sizes, int n_in,
                              void* d_out, int out_size, void* d_ws, size_t ws_size,
                              hipStream_t stream) {
    const float* loc   = (const float*)d_in[0];
    const float* conf  = (const float*)d_in[1];
    const float* prior = (const float*)d_in[2];
    float* out = (float*)d_out;

    char* ws = (char*)d_ws;
    const size_t candBytes = (size_t)B_ * C_ * CAP * sizeof(unsigned long long); // 10.6 MB
    unsigned long long* cand = (unsigned long long*)ws;
    unsigned* cnt   = (unsigned*)(ws + candBytes);            // B_*C_ counters
    unsigned* bflag = cnt + (size_t)B_ * C_;                  // B_ flags (contiguous)

    hipMemsetAsync(cnt, 0, (size_t)(B_ * C_ + B_) * sizeof(unsigned), stream);

    k_filter<<<B_ * NCH, 256, 0, stream>>>(conf, cand, cnt, bflag);
    k_nms   <<<B_ * C_,  256, 0, stream>>>(cand, cnt, bflag, conf, loc, prior, out);
}

// Round 15
// 140.354 us; speedup vs baseline: 1.0571x; 1.0571x over previous
//
#include <hip/hip_runtime.h>
#include <hip/hip_bf16.h>
#include <math.h>

// Problem constants (fixed by setup_inputs)
constexpr int B_ = 32;
constexpr int P_ = 24564;
constexpr int C_ = 81;
constexpr int K_ = 200;

constexpr int NCH = 64;           // chunks per image
constexpr int CPR = 384;          // rows per chunk; 64*384 = 24576 >= 24564
constexpr int SCAP = 1024;        // per-block LDS staging capacity (expect ~404)
constexpr int CAP  = 512;         // per-task candidate capacity (expect ~322)
constexpr float T_SEL = 0.9869f;  // static prune threshold; mean count ~322 > 200 (6.8 sigma)
                                  // soundness: count>=200 above T => true top-200 all > T;
                                  // violations detected at runtime -> exact fallback.
// All candidate scores lie in (T_SEL, 1.0) => key bits[63:51] constant =>
// bits[50:43] are the discriminating radix digit for the cut.

// ---------------------------------------------------------------------------
// K1 (only conf pass): stream slab coalesced, stage score>T candidates in LDS,
// reserve per-class ranges with ONE global atomic per (block,class), scatter.
// ---------------------------------------------------------------------------
__global__ __launch_bounds__(256) void k_filter(const float* __restrict__ conf,
                                                unsigned long long* __restrict__ cand,
                                                unsigned* __restrict__ cnt,
                                                unsigned* __restrict__ bflag) {
    __shared__ unsigned long long skey[SCAP];   // 8 KB
    __shared__ unsigned short scls[SCAP];       // 2 KB
    __shared__ unsigned scnt[C_], sbase[C_], scnt2[C_];
    __shared__ unsigned sn;
    const int bid = blockIdx.x;
    const int b = bid / NCH, ch = bid % NCH;
    const int tid = threadIdx.x;

    for (int i = tid; i < C_; i += 256) { scnt[i] = 0; scnt2[i] = 0; }
    if (tid == 0) sn = 0;
    __syncthreads();

    const int p0 = ch * CPR;
    const int rows = min(CPR, P_ - p0);
    const float* slab = conf + ((size_t)b * P_ + (size_t)p0) * C_;
    const int n4 = rows * C_ / 4;               // rows%4==0 -> exact
    for (int g = tid; g < n4; g += 256) {
        float4 v = ((const float4*)slab)[g];
        int e = g * 4;
        int c = e % C_;
        int pl = e / C_;
        float s[4] = {v.x, v.y, v.z, v.w};
#pragma unroll
        for (int j = 0; j < 4; ++j) {
            int cj = c + j, pj = pl;
            if (cj >= C_) { cj -= C_; pj += 1; }
            float sv = s[j];
            if (sv > T_SEL && cj != 0) {        // class 0 (background) never output
                unsigned pos = atomicAdd(&sn, 1u);
                if (pos < (unsigned)SCAP) {
                    unsigned pg = (unsigned)(p0 + pj);
                    skey[pos] = ((unsigned long long)__float_as_uint(sv) << 32) | (~pg);
                    scls[pos] = (unsigned short)cj;
                    atomicAdd(&scnt[cj], 1u);
                } else {
                    bflag[b] = 1u;              // staging overflow -> image fallback
                }
            }
        }
    }
    __syncthreads();
    if (tid < C_) sbase[tid] = scnt[tid] ? atomicAdd(&cnt[b * C_ + tid], scnt[tid]) : 0u;
    __syncthreads();
    const int m = (int)min(sn, (unsigned)SCAP);
    for (int i = tid; i < m; i += 256) {
        int c = scls[i];
        unsigned pos = sbase[c] + atomicAdd(&scnt2[c], 1u);
        if (pos < (unsigned)CAP)
            cand[((size_t)(b * C_ + c)) * CAP + pos] = skey[i];
        // pos >= CAP  =>  cnt[task] > CAP  => task falls back (detected in k_nms)
    }
}

// ---------------------------------------------------------------------------
// K2: reg-staged keys -> radix cut (wave-agg compact) -> n-bounded full-u64
// rank-sort -> decode by rank -> eager IoU masks (sentinel columns, guard-free
// predicate, diagonal post-mask) -> wave-0 bit scan -> direct global output.
// ---------------------------------------------------------------------------
__global__ __launch_bounds__(256) void k_nms(const unsigned long long* __restrict__ cand,
                                             const unsigned* __restrict__ cnt,
                                             const unsigned* __restrict__ bflag,
                                             const float* __restrict__ conf,
                                             const float* __restrict__ loc,
                                             const float* __restrict__ prior,
                                             float* __restrict__ out) {
#pragma clang fp contract(off)
    __shared__ __align__(16) unsigned long long masks[K_][4];   // 6400 B
    __shared__ __align__(16) unsigned long long top[256];       // 2048 B (cut survivors)
    __shared__ __align__(16) float4 bbox[K_];                   // 3200 B rank-indexed
    __shared__ float sc[K_], bar[K_];
    __shared__ unsigned char vflag[K_];
    __shared__ unsigned long long keepw[4];
    __shared__ unsigned kpre[4];
    __shared__ unsigned long long sh_prefix;
    __shared__ unsigned sh_rank, sh_cnt2, sh_cut, sh_fat;

    // aliases inside masks[] (all dead before the IoU mask build):
    unsigned long long* buf = &masks[0][0];             // 512 u64 (fb / fat staging)
    unsigned* rs_hist = (unsigned*)&masks[128][0];      // 256 u32 (cut hist / fb radix)
    unsigned* rs_sf   = (unsigned*)&masks[160][0];      // 256 u32 (fb radix)

    const int bid = blockIdx.x;
    const int b = bid / C_, c = bid % C_;
    const int tid = threadIdx.x;
    const int lane = tid & 63;
    float* obase = out + ((size_t)(b * C_ + c)) * (K_ * 5);

    if (c == 0) {                               // background rows: all zeros
        float4 z = make_float4(0.f, 0.f, 0.f, 0.f);
        for (int i = tid; i < K_ * 5 / 4; i += 256) ((float4*)obase)[i] = z;
        return;
    }

    const int task = b * C_ + c;
    const unsigned long long* crow = cand + (size_t)task * CAP;
    const unsigned cn = cnt[task];
    const bool fb = (bflag[b] != 0u) || (cn < (unsigned)K_) || (cn > (unsigned)CAP);

    int n;
    int snum = 0;                               // survivor count in top[]
    bool fat = false;
    if (!fb) {
        n = (int)cn;                            // 200 <= n <= CAP
        const unsigned long long k1 = (tid < n)       ? crow[tid]       : 0ull;
        const unsigned long long k2 = (tid + 256 < n) ? crow[tid + 256] : 0ull;
        if (n <= 256) {
            top[tid] = k1;
            snum = n;
            __syncthreads();
        } else {
            rs_hist[tid] = 0u;
            top[tid] = 0ull;
            __syncthreads();
            atomicAdd(&rs_hist[(unsigned)((k1 >> 43) & 255ull)], 1u);   // tid < n (n>256)
            if (tid + 256 < n)
                atomicAdd(&rs_hist[(unsigned)((k2 >> 43) & 255ull)], 1u);
            __syncthreads();
            // wave-0 suffix scan over 256 bins (4 bins/lane), pick cut digit
            if (tid < 64) {
                const int l = tid;
                uint4 h = *(const uint4*)&rs_hist[l * 4];
                unsigned s3 = h.w;
                unsigned s2 = h.z + s3;
                unsigned s1 = h.y + s2;
                unsigned s0 = h.x + s1;
                unsigned acc = s0;
                for (int off = 1; off < 64; off <<= 1) {
                    unsigned o = __shfl_down(acc, off, 64);
                    if (l + off < 64) acc += o;
                }
                const unsigned suf_after = acc - s0;     // sum over lanes > l
                unsigned long long bal = __ballot(s0 + suf_after >= (unsigned)K_);
                int hl = 63 - __builtin_clzll(bal);      // lane 0 suffix = n >= 257
                if (l == hl) {
                    int k; unsigned sufk;
                    if      (s3 + suf_after >= (unsigned)K_) { k = 3; sufk = s3 + suf_after; }
                    else if (s2 + suf_after >= (unsigned)K_) { k = 2; sufk = s2 + suf_after; }
                    else if (s1 + suf_after >= (unsigned)K_) { k = 1; sufk = s1 + suf_after; }
                    else                                     { k = 0; sufk = s0 + suf_after; }
                    sh_cut = (unsigned)(l * 4 + k);
                    sh_fat = (sufk > 256u) ? 1u : 0u;
                    sh_cnt2 = 0u;
                }
            }
            __syncthreads();
            fat = (sh_fat != 0u);
            if (!fat) {
                // wave-aggregated compact of survivors into top[] (exact set)
                const unsigned cut = sh_cut;
                {
                    bool q = ((unsigned)((k1 >> 43) & 255ull) >= cut);   // tid < n
                    unsigned long long bal = __ballot(q);
                    unsigned pre = (unsigned)__popcll(bal & ((1ull << lane) - 1ull));
                    unsigned wb = 0;
                    if (lane == 0) {
                        unsigned cw = (unsigned)__popcll(bal);
                        if (cw) wb = atomicAdd(&sh_cnt2, cw);
                    }
                    wb = (unsigned)__shfl((int)wb, 0, 64);
                    if (q) top[wb + pre] = k1;
                }
                {
                    bool q = (tid + 256 < n) && ((unsigned)((k2 >> 43) & 255ull) >= cut);
                    unsigned long long bal = __ballot(q);
                    unsigned pre = (unsigned)__popcll(bal & ((1ull << lane) - 1ull));
                    unsigned wb = 0;
                    if (lane == 0) {
                        unsigned cw = (unsigned)__popcll(bal);
                        if (cw) wb = atomicAdd(&sh_cnt2, cw);
                    }
                    wb = (unsigned)__shfl((int)wb, 0, 64);
                    if (q) top[wb + pre] = k2;
                }
                __syncthreads();
                snum = (int)sh_cnt2;            // 200..256
            } else {
                // degenerate digit distribution (essentially never): stage 512
                buf[tid] = k1;
                buf[tid + 256] = k2;
                __syncthreads();
            }
        }
    } else {
        // ---- exact fallback from the strided global column (rare/never) ----
        for (int i = tid; i < CAP; i += 256) buf[i] = 0ull;
        const float* col = conf + (size_t)b * P_ * C_ + c;
        unsigned lc = 0;
        for (int p = tid; p < P_; p += 256)
            if (col[(size_t)p * C_] > 0.01f) lc++;
        rs_sf[tid] = lc;
        __syncthreads();
        for (int off = 128; off > 0; off >>= 1) {
            if (tid < off) rs_sf[tid] += rs_sf[tid + off];
            __syncthreads();
        }
        const unsigned total = rs_sf[0];
        unsigned long long t200v = 1ull;
        if (total > (unsigned)K_) {
            if (tid == 0) { sh_prefix = 0ull; sh_rank = (unsigned)K_; }
            __syncthreads();
            for (int d = 7; d >= 0; --d) {
                rs_hist[tid] = 0;
                __syncthreads();
                const unsigned long long pref = sh_prefix;
                const unsigned rank = sh_rank;
                for (int p = tid; p < P_; p += 256) {
                    float sv = col[(size_t)p * C_];
                    if (sv > 0.01f) {
                        unsigned long long key =
                            ((unsigned long long)__float_as_uint(sv) << 32) | (~(unsigned)p);
                        bool match = (d == 7) || (((key ^ pref) >> ((d + 1) * 8)) == 0ull);
                        if (match) atomicAdd(&rs_hist[(unsigned)((key >> (d * 8)) & 255ull)], 1u);
                    }
                }
                __syncthreads();
                rs_sf[tid] = rs_hist[tid];
                __syncthreads();
                for (int off = 1; off < 256; off <<= 1) {
                    unsigned v2 = (tid + off < 256) ? rs_sf[tid + off] : 0u;
                    __syncthreads();
                    rs_sf[tid] += v2;
                    __syncthreads();
                }
                if (rs_sf[tid] >= rank && (tid == 255 || rs_sf[tid + 1] < rank)) {
                    sh_prefix = pref | ((unsigned long long)tid << (d * 8));
                    sh_rank = rank - ((tid == 255) ? 0u : rs_sf[tid + 1]);
                }
                __syncthreads();
            }
            t200v = sh_prefix;
        }
        if (tid == 0) sh_cnt2 = 0;
        __syncthreads();
        for (int p = tid; p < P_; p += 256) {
            float sv = col[(size_t)p * C_];
            if (sv > 0.01f) {
                unsigned long long key =
                    ((unsigned long long)__float_as_uint(sv) << 32) | (~(unsigned)p);
                if (key >= t200v) {
                    unsigned pos = atomicAdd(&sh_cnt2, 1u);
                    if (pos < (unsigned)CAP) buf[pos] = key;   // <=200 qualify (keys unique)
                }
            }
        }
        __syncthreads();
        n = (int)min(sh_cnt2, (unsigned)CAP);   // <= 200
        top[tid] = (tid < n) ? buf[tid] : 0ull;
        snum = n;
        __syncthreads();
    }

    const int nsel = min(n, K_);

    // ---- full-u64 rank-sort (n-bounded) and decode scattered by rank -------
    auto decode_to = [&](unsigned long long key, int r) {
        unsigned ub = (unsigned)(key >> 32);
        unsigned p = ~((unsigned)key);
        float score = __uint_as_float(ub);
        bool v = ((ub & 0x7F800000u) != 0x7F800000u);   // isfinite
        const float4 l4 = ((const float4*)loc)[(size_t)b * P_ + p];
        const float4 p4 = ((const float4*)prior)[p];
        float cx = p4.x + (l4.x * 0.1f) * p4.z;
        float cy = p4.y + (l4.y * 0.1f) * p4.w;
        float w  = p4.z * expf(l4.z * 0.2f);
        float h  = p4.w * expf(l4.w * 0.2f);
        float x1 = cx - w * 0.5f;
        float y1 = cy - h * 0.5f;
        float x2 = x1 + w;
        float y2 = y1 + h;
        bbox[r] = make_float4(x1, y1, x2, y2);
        sc[r] = score;
        bar[r] = (x2 - x1) * (y2 - y1);
        vflag[r] = v ? (unsigned char)1 : (unsigned char)0;
    };

    if (!fat) {
        const unsigned long long k = top[tid];
        int r = 0;
        const int mm = (snum + 3) & ~3;         // zeros beyond snum never outrank k
        for (int i = 0; i < mm; i += 4) {
            ulonglong2 a = *(const ulonglong2*)&top[i];
            ulonglong2 d = *(const ulonglong2*)&top[i + 2];
            r += (a.x > k) + (a.y > k) + (d.x > k) + (d.y > k);
        }
        if (k != 0ull && r < K_) decode_to(k, r);
    } else {
        const unsigned long long k1 = buf[tid];
        const unsigned long long k2 = buf[tid + 256];
        int r1 = 0, r2 = 0;
        for (int i = 0; i < CAP; i += 4) {
            ulonglong2 a = *(const ulonglong2*)&buf[i];
            ulonglong2 d = *(const ulonglong2*)&buf[i + 2];
            r1 += (a.x > k1) + (a.y > k1) + (d.x > k1) + (d.y > k1);
            r2 += (a.x > k2) + (a.y > k2) + (d.x > k2) + (d.y > k2);
        }
        if (k1 != 0ull && r1 < K_) decode_to(k1, r1);
        if (k2 != 0ull && r2 < K_) decode_to(k2, r2);
    }
    if (tid >= nsel && tid < K_) {              // tail rows: sentinel (never intersect)
        bbox[tid] = make_float4(1e30f, 1e30f, 1e30f, 1e30f);
        sc[tid] = 0.f; bar[tid] = 0.f; vflag[tid] = 0;
    }
    __syncthreads();                            // aliases dead -> masks writable

    // ---- eager IoU masks: sentinel columns, guard-free predicate, diagonal
    // post-mask. RN(inter/uni) > 0.45f <=> inter > M*uni (exact in f64).
    const double M_IOU = 0.5 * ((double)__uint_as_float(0x3EE66666u) +
                                (double)__uint_as_float(0x3EE66667u));
    const int nv = nsel;
    const int wid = tid >> 6;

    float4 jb[4]; float jar[4];
#pragma unroll
    for (int w = 0; w < 4; ++w) {
        int j = w * 64 + lane;
        bool in = (j < K_);
        jb[w]  = in ? bbox[j] : make_float4(1e30f, 1e30f, 1e30f, 1e30f);
        jar[w] = in ? bar[j] : 0.f;
    }

    for (int idx = tid; idx < K_ * 4; idx += 256) {
        int i = idx >> 2, w = idx & 3;
        if (w < (i >> 6)) masks[i][w] = 0ull;
    }
    for (int i = wid; i < nv; i += 4) {
        float4 rb = bbox[i];
        float r_ar = bar[i];
        const int w0 = i >> 6;
        const unsigned long long dmask = (0xFFFFFFFFFFFFFFFEull << (i & 63));
#pragma unroll
        for (int w = 0; w < 4; ++w) {
            if (w >= w0) {
                float xx1 = fmaxf(rb.x, jb[w].x);
                float yy1 = fmaxf(rb.y, jb[w].y);
                float xx2 = fminf(rb.z, jb[w].z);
                float yy2 = fminf(rb.w, jb[w].w);
                float iw = fmaxf(xx2 - xx1, 0.0f);
                float ih = fmaxf(yy2 - yy1, 0.0f);
                float inter = iw * ih;
                float uni = (r_ar + jar[w]) - inter;
                bool pred = (uni > 0.0f) && ((double)inter > M_IOU * (double)uni);
                unsigned long long m = __ballot(pred);
                if (w == w0) m &= dmask;        // enforce j > i on diagonal word
                if (lane == 0) masks[i][w] = m;
            }
        }
    }
    __syncthreads();

    // ---- greedy suppression: wave 0, uniform lanes, kept-nonzero-rows loop.
    if (tid < 64) {
        const int l = tid;
        unsigned long long V0 = __ballot((l       < nv) && vflag[l]);
        unsigned long long V1 = __ballot((64 + l  < nv) && vflag[64 + l]);
        unsigned long long V2 = __ballot((128 + l < nv) && vflag[128 + l]);
        unsigned long long V3 = __ballot((192 + l < nv) && vflag[192 + l]);
        auto rownz = [&](int r) -> bool {
            if (r >= nv) return false;
            return (masks[r][0] | masks[r][1] | masks[r][2] | masks[r][3]) != 0ull;
        };
        unsigned long long R0 = __ballot(rownz(l))       & V0;
        unsigned long long R1 = __ballot(rownz(64 + l))  & V1;
        unsigned long long R2 = __ballot(rownz(128 + l)) & V2;
        unsigned long long R3 = __ballot(rownz(192 + l)) & V3;

        unsigned long long S0 = 0, S1 = 0, S2 = 0, S3 = 0;
        while (true) {
            unsigned long long t;
            int i = -1;
            if ((t = R0 & ~S0) != 0ull)      i = (int)__builtin_ctzll(t);
            else if ((t = R1 & ~S1) != 0ull) i = 64 + (int)__builtin_ctzll(t);
            else if ((t = R2 & ~S2) != 0ull) i = 128 + (int)__builtin_ctzll(t);
            else if ((t = R3 & ~S3) != 0ull) i = 192 + (int)__builtin_ctzll(t);
            if (i < 0) break;
            const unsigned long long bit = 1ull << (i & 63);
            const int slot = i >> 6;
            if (slot == 0) R0 ^= bit; else if (slot == 1) R1 ^= bit;
            else if (slot == 2) R2 ^= bit; else R3 ^= bit;
            ulonglong2 m01 = *(const ulonglong2*)&masks[i][0];
            ulonglong2 m23 = *(const ulonglong2*)&masks[i][2];
            S0 |= m01.x; S1 |= m01.y; S2 |= m23.x; S3 |= m23.y;
        }
        if (l == 0) {
            unsigned long long K0 = V0 & ~S0, K1 = V1 & ~S1, K2 = V2 & ~S2, K3 = V3 & ~S3;
            keepw[0] = K0; keepw[1] = K1; keepw[2] = K2; keepw[3] = K3;
            kpre[0] = 0;
            kpre[1] = (unsigned)__popcll(K0);
            kpre[2] = kpre[1] + (unsigned)__popcll(K1);
            kpre[3] = kpre[2] + (unsigned)__popcll(K2);
        }
    }
    __syncthreads();

    // ---- direct global output: kept rows scattered, tail zero-filled -------
    if (tid < K_) {
        int w = tid >> 6, bit = tid & 63;
        if ((keepw[w] >> bit) & 1ull) {
            unsigned slot = kpre[w] + (unsigned)__popcll(keepw[w] & ((1ull << bit) - 1ull));
            float4 bb = bbox[tid];
            float* o = obase + slot * 5;
            o[0] = sc[tid]; o[1] = bb.x; o[2] = bb.y; o[3] = bb.z; o[4] = bb.w;
        }
    }
    {
        const unsigned keptTotal = kpre[3] + (unsigned)__popcll(keepw[3]);
        const int zbase = (int)keptTotal * 5;
        const int ztot = K_ * 5 - zbase;
        for (int e = tid; e < ztot; e += 256) obase[zbase + e] = 0.0f;
    }
}

// ---------------------------------------------------------------------------
extern "C" void kernel_launch(void* const* d_in, const int* in_sizes, int n_in,
                              void* d_out, int out_size, void* d_ws, size_t ws_size,
                              hipStream_t stream) {
    const float* loc   = (const float*)d_in[0];
    const float* conf  = (const float*)d_in[1];
    const float* prior = (const float*)d_in[2];
    float* out = (float*)d_out;

    char* ws = (char*)d_ws;
    const size_t candBytes = (size_t)B_ * C_ * CAP * sizeof(unsigned long long); // 10.6 MB
    unsigned long long* cand = (unsigned long long*)ws;
    unsigned* cnt   = (unsigned*)(ws + candBytes);            // B_*C_ counters
    unsigned* bflag = cnt + (size_t)B_ * C_;                  // B_ flags (contiguous)

    hipMemsetAsync(cnt, 0, (size_t)(B_ * C_ + B_) * sizeof(unsigned), stream);

    k_filter<<<B_ * NCH, 256, 0, stream>>>(conf, cand, cnt, bflag);
    k_nms   <<<B_ * C_,  256, 0, stream>>>(cand, cnt, bflag, conf, loc, prior, out);
}